// Round 20
// baseline (263.059 us; speedup 1.0000x reference)
//
#include <hip/hip_runtime.h>
#include <hip/hip_bf16.h>
#include <math.h>

#define N_NODES 100000
#define N_EDGES 800000
#define NB_SCAN ((N_NODES + 1023) / 1024)   // 98
#define GB1 ((N_NODES + 31)/32)             // 3125 row tiles
#define SB  ((N_EDGES + 255)/256)           // 3125 edge blocks
#define PG1 1024                            // persistent gemm1 grid (4 blocks/CU)
#define NBINS 256

typedef __bf16 bf16x8 __attribute__((ext_vector_type(8)));
typedef float  f32x4  __attribute__((ext_vector_type(4)));

__device__ __forceinline__ float lrelu(float v){ return v > 0.f ? v : 0.2f*v; }
__device__ __forceinline__ float eluf(float v){ return v > 0.f ? v : (__expf(v) - 1.f); }

__device__ __forceinline__ unsigned short f2bf(float f){
    union { float f; unsigned u; } v; v.f = f;
    unsigned r = (v.u + 0x7fff + ((v.u >> 16) & 1)) >> 16;
    return (unsigned short)r;
}
__device__ __forceinline__ float bf2f(unsigned short u){
    union { unsigned u; float f; } v; v.u = ((unsigned)u) << 16;
    return v.f;
}
// fp8 e4m3 (OCP on gfx950) encode via HW convert
__device__ __forceinline__ unsigned char f2fp8(float v){
    return (unsigned char)(__builtin_amdgcn_cvt_pk_fp8_f32(v, v, 0, false) & 0xff);
}

// ---------- setup ----------
__global__ __launch_bounds__(256) void setup_kernel(
    const float* __restrict__ W1, const float* __restrict__ W2,
    unsigned short* __restrict__ wt1, unsigned short* __restrict__ wt2,
    int* __restrict__ counts, float* __restrict__ lacc)
{
    int i = blockIdx.x*256 + threadIdx.x;
    if (i < N_NODES) counts[i] = 0;
    if (i < 2*NBINS) lacc[i] = 0.f;
    if (i < 128*128){
        int n = i >> 7, k = i & 127;
        wt1[i] = f2bf(W1[k*128 + n]);
    }
    if (i < 112*128){
        int n = i >> 7, k = i & 127;
        wt2[i] = (n < 100) ? f2bf(W2[k*100 + n]) : (unsigned short)0;
    }
}

// ---------- CSR build: count + rank capture ----------
__global__ __launch_bounds__(256) void count_kernel(const int* __restrict__ ei,
                                                    int* __restrict__ counts,
                                                    int* __restrict__ rank){
    int e = blockIdx.x*256 + threadIdx.x;
    if (e < N_EDGES){
        int d = ei[N_EDGES + e];
        rank[e] = atomicAdd(&counts[d], 1);
    }
}

__global__ __launch_bounds__(1024) void scan_blocks_kernel(const int* __restrict__ counts,
                                                           int* __restrict__ exoffs,
                                                           int* __restrict__ bsums){
    __shared__ int buf[1024];
    int t = threadIdx.x;
    int gid = blockIdx.x*1024 + t;
    int v = (gid < N_NODES) ? counts[gid] : 0;
    buf[t] = v;
    __syncthreads();
    #pragma unroll
    for (int off = 1; off < 1024; off <<= 1){
        int u = (t >= off) ? buf[t-off] : 0;
        __syncthreads();
        buf[t] += u;
        __syncthreads();
    }
    if (gid < N_NODES) exoffs[gid] = buf[t] - v;
    if (t == 1023) bsums[blockIdx.x] = buf[1023];
}

// scan_add computes its own block prefix over bsums (scan_sums folded in)
__global__ __launch_bounds__(1024) void scan_add_kernel(const int* __restrict__ exoffs,
                                                        const int* __restrict__ bsums,
                                                        int* __restrict__ offs){
    __shared__ int sb[128];
    int t = threadIdx.x;
    if (t < 128){
        int lim = min((int)blockIdx.x, NB_SCAN);
        sb[t] = (t < lim) ? bsums[t] : 0;
    }
    __syncthreads();
    #pragma unroll
    for (int off = 64; off >= 1; off >>= 1){
        if (t < off) sb[t] += sb[t + off];
        __syncthreads();
    }
    int pre = sb[0];
    int gid = blockIdx.x*1024 + t;
    if (gid < N_NODES){
        offs[gid] = exoffs[gid] + pre;
    }
    if (gid == 0) offs[N_NODES] = N_EDGES;
}

// ---------- scatter: atomic-free, ONE random write per edge ----------
__global__ __launch_bounds__(256) void scatter_kernel(
    const int* __restrict__ ei, const int* __restrict__ offs, const int* __restrict__ rank,
    int* __restrict__ csr_src)
{
    int e = blockIdx.x*256 + threadIdx.x;
    if (e >= N_EDGES) return;
    int s = ei[e];
    int d = ei[N_EDGES + e];
    csr_src[offs[d] + rank[e]] = s;
}

// ---------- GEMM1 persistent-W ----------
__global__ __launch_bounds__(256) void gemm1_mfma(
    const float* __restrict__ x, const unsigned short* __restrict__ wt1,
    const float* __restrict__ a_src, const float* __restrict__ a_dst,
    unsigned short* __restrict__ h1bf, float* __restrict__ as1, float* __restrict__ ad1)
{
    __shared__ unsigned short Al[32*128];   // 8 KB, XOR-swizzled
    __shared__ unsigned short Bl[128*128];  // 32 KB, XOR-swizzled (staged ONCE)
    int t = threadIdx.x;

    #pragma unroll
    for (int i = 0; i < 8; i++){
        int idx = (i*256 + t)*8;
        int n = idx >> 7, c = idx & 127;
        bf16x8 v = *(const bf16x8*)(wt1 + n*128 + c);
        int byte = (n*256 + c*2) ^ ((n&7)<<4);
        *(bf16x8*)((char*)Bl + byte) = v;
    }

    int wv = t >> 6, l = t & 63;
    int wm = wv >> 1, wn = wv & 1;
    int lr = l & 15, lg = l >> 4;

    for (int tile = blockIdx.x; tile < GB1; tile += PG1){
        int row0 = tile*32;
        #pragma unroll
        for (int i = 0; i < 2; i++){
            int idx = (i*256 + t)*8;
            int r = idx >> 7, c = idx & 127;
            int grow = row0 + r;
            bf16x8 v;
            if (grow < N_NODES){
                const float4* p = (const float4*)(x + (size_t)grow*128 + c);
                float4 f0 = p[0], f1 = p[1];
                v[0]=(__bf16)f0.x; v[1]=(__bf16)f0.y; v[2]=(__bf16)f0.z; v[3]=(__bf16)f0.w;
                v[4]=(__bf16)f1.x; v[5]=(__bf16)f1.y; v[6]=(__bf16)f1.z; v[7]=(__bf16)f1.w;
            } else {
                #pragma unroll
                for (int j = 0; j < 8; j++) v[j] = (__bf16)0.f;
            }
            int byte = (r*256 + c*2) ^ ((r&7)<<4);
            *(bf16x8*)((char*)Al + byte) = v;
        }
        __syncthreads();

        bf16x8 af[4];
        #pragma unroll
        for (int ks = 0; ks < 4; ks++){
            int r = wm*16 + lr;
            int byte = (r*256 + (ks*32 + lg*8)*2) ^ ((r&7)<<4);
            af[ks] = *(const bf16x8*)((const char*)Al + byte);
        }
        f32x4 acc[4];
        #pragma unroll
        for (int nt = 0; nt < 4; nt++){
            acc[nt] = (f32x4){0.f,0.f,0.f,0.f};
            #pragma unroll
            for (int ks = 0; ks < 4; ks++){
                int n = wn*64 + nt*16 + lr;
                int byte = (n*256 + (ks*32 + lg*8)*2) ^ ((n&7)<<4);
                bf16x8 bfv = *(const bf16x8*)((const char*)Bl + byte);
                acc[nt] = __builtin_amdgcn_mfma_f32_16x16x32_bf16(af[ks], bfv, acc[nt], 0, 0, 0);
            }
        }
        int orow_base = row0 + wm*16 + lg*4;
        #pragma unroll
        for (int nt = 0; nt < 4; nt++){
            int colb = wn*64 + nt*16;
            int head = colb >> 4;
            float avs = a_src[colb + lr];
            float avd = a_dst[colb + lr];
            #pragma unroll
            for (int r = 0; r < 4; r++){
                int grow = orow_base + r;
                float v = acc[nt][r];
                if (grow < N_NODES) h1bf[(size_t)grow*128 + colb + lr] = f2bf(v);
                float ps = v*avs, pd = v*avd;
                ps += __shfl_xor(ps,1); ps += __shfl_xor(ps,2); ps += __shfl_xor(ps,4); ps += __shfl_xor(ps,8);
                pd += __shfl_xor(pd,1); pd += __shfl_xor(pd,2); pd += __shfl_xor(pd,4); pd += __shfl_xor(pd,8);
                if (lr == 0 && grow < N_NODES){
                    as1[grow*8 + head] = ps;
                    ad1[grow*8 + head] = pd;
                }
            }
        }
        __syncthreads();
    }
}

// ---------- agg layer1: one wave per dst; inline exp, 4-deep unroll ----------
__global__ __launch_bounds__(256) void agg1_kernel(
    const int* __restrict__ offs, const int* __restrict__ csr_src,
    const float* __restrict__ as1, const float* __restrict__ ad1,
    const unsigned short* __restrict__ h1bf, const float* __restrict__ b1,
    float* __restrict__ emb1_out /* d_out + 1 */)
{
    int wave = threadIdx.x >> 6;
    int lane = threadIdx.x & 63;
    int d = blockIdx.x*4 + wave;
    if (d >= N_NODES) return;
    int h = lane >> 3;
    int col = 2*lane;
    int e0 = offs[d], e1 = offs[d+1];
    float ad = ad1[d*8 + h];
    float acc0 = 0.f, acc1 = 0.f, wsum = 0.f;

    for (int base = e0; base < e1; base += 64){
        int ii = base + lane;
        int sv = (ii < e1) ? csr_src[ii] : 0;
        int n = min(64, e1 - base);
        int i = 0;
        for (; i + 3 < n; i += 4){
            int s0 = __shfl(sv, i);
            int s1 = __shfl(sv, i+1);
            int s2 = __shfl(sv, i+2);
            int s3 = __shfl(sv, i+3);
            float l0 = as1[s0*8 + h];
            float l1 = as1[s1*8 + h];
            float l2 = as1[s2*8 + h];
            float l3 = as1[s3*8 + h];
            unsigned hv0 = *(const unsigned*)(h1bf + (size_t)s0*128 + col);
            unsigned hv1 = *(const unsigned*)(h1bf + (size_t)s1*128 + col);
            unsigned hv2 = *(const unsigned*)(h1bf + (size_t)s2*128 + col);
            unsigned hv3 = *(const unsigned*)(h1bf + (size_t)s3*128 + col);
            float w0 = __expf(lrelu(l0 + ad));
            float w1 = __expf(lrelu(l1 + ad));
            float w2 = __expf(lrelu(l2 + ad));
            float w3 = __expf(lrelu(l3 + ad));
            acc0 += w0*bf2f((unsigned short)hv0) + w1*bf2f((unsigned short)hv1)
                  + w2*bf2f((unsigned short)hv2) + w3*bf2f((unsigned short)hv3);
            acc1 += w0*bf2f((unsigned short)(hv0>>16)) + w1*bf2f((unsigned short)(hv1>>16))
                  + w2*bf2f((unsigned short)(hv2>>16)) + w3*bf2f((unsigned short)(hv3>>16));
            wsum += (w0 + w1) + (w2 + w3);
        }
        for (; i < n; i++){
            int s0 = __shfl(sv, i);
            float w0 = __expf(lrelu(as1[s0*8 + h] + ad));
            unsigned hv0 = *(const unsigned*)(h1bf + (size_t)s0*128 + col);
            acc0 += w0*bf2f((unsigned short)hv0);
            acc1 += w0*bf2f((unsigned short)(hv0>>16));
            wsum += w0;
        }
    }
    float inv = 1.f/(wsum + 1e-16f);
    emb1_out[(size_t)d*128 + col]     = acc0*inv + b1[col];
    emb1_out[(size_t)d*128 + col + 1] = acc1*inv + b1[col+1];
}

// ---------- GEMM2 (non-persistent, LDS union): h2 (fp8) + fused alpha2 (f32) ----------
__global__ __launch_bounds__(256) void gemm2_mfma(
    const float* __restrict__ emb1g /* d_out+1 */, const unsigned short* __restrict__ wt2,
    const float* __restrict__ a_src2, const float* __restrict__ a_dst2,
    unsigned char* __restrict__ h2f8, float* __restrict__ as2, float* __restrict__ ad2)
{
    __shared__ __align__(16) char smem[36864];          // 8K (Al) + 28K (Bl)
    unsigned short* Al = (unsigned short*)smem;         // 32*128
    unsigned short* Bl = Al + 32*128;                   // 112*128
    float* Hl = (float*)smem;                           // reused: 32*113 f32

    int t = threadIdx.x;
    int row0 = blockIdx.x*32;

    #pragma unroll
    for (int i = 0; i < 2; i++){
        int idx = (i*256 + t)*8;
        int r = idx >> 7, c = idx & 127;
        int grow = row0 + r;
        bf16x8 v;
        if (grow < N_NODES){
            const float4* p = (const float4*)(emb1g + (size_t)grow*128 + c);
            float4 f0 = p[0], f1 = p[1];
            v[0]=(__bf16)eluf(f0.x); v[1]=(__bf16)eluf(f0.y); v[2]=(__bf16)eluf(f0.z); v[3]=(__bf16)eluf(f0.w);
            v[4]=(__bf16)eluf(f1.x); v[5]=(__bf16)eluf(f1.y); v[6]=(__bf16)eluf(f1.z); v[7]=(__bf16)eluf(f1.w);
        } else {
            #pragma unroll
            for (int j = 0; j < 8; j++) v[j] = (__bf16)0.f;
        }
        int byte = (r*256 + c*2) ^ ((r&7)<<4);
        *(bf16x8*)((char*)Al + byte) = v;
    }
    #pragma unroll
    for (int i = 0; i < 7; i++){
        int idx = (i*256 + t)*8;
        int n = idx >> 7, c = idx & 127;
        bf16x8 v = *(const bf16x8*)(wt2 + n*128 + c);
        int byte = (n*256 + c*2) ^ ((n&7)<<4);
        *(bf16x8*)((char*)Bl + byte) = v;
    }
    __syncthreads();

    int wv = t >> 6, l = t & 63;
    int wm = wv >> 1, wn = wv & 1;
    int lr = l & 15, lg = l >> 4;
    bf16x8 af[4];
    #pragma unroll
    for (int ks = 0; ks < 4; ks++){
        int r = wm*16 + lr;
        int byte = (r*256 + (ks*32 + lg*8)*2) ^ ((r&7)<<4);
        af[ks] = *(const bf16x8*)((const char*)Al + byte);
    }
    int ntmax = wn ? 3 : 4;
    f32x4 acc[4];
    for (int nt = 0; nt < ntmax; nt++){
        acc[nt] = (f32x4){0.f,0.f,0.f,0.f};
        #pragma unroll
        for (int ks = 0; ks < 4; ks++){
            int n = wn*64 + nt*16 + lr;
            int byte = (n*256 + (ks*32 + lg*8)*2) ^ ((n&7)<<4);
            bf16x8 bfv = *(const bf16x8*)((const char*)Bl + byte);
            acc[nt] = __builtin_amdgcn_mfma_f32_16x16x32_bf16(af[ks], bfv, acc[nt], 0, 0, 0);
        }
    }
    int orow_base = row0 + wm*16 + lg*4;
    for (int nt = 0; nt < ntmax; nt++){
        int col = wn*64 + nt*16 + lr;
        if (col < 100){
            #pragma unroll
            for (int r = 0; r < 4; r++){
                int grow = orow_base + r;
                if (grow < N_NODES) h2f8[(size_t)grow*100 + col] = f2fp8(acc[nt][r]);
            }
        }
    }
    __syncthreads();   // all LDS (Al/Bl) reads done -> safe to reuse as Hl
    for (int nt = 0; nt < ntmax; nt++){
        int col = wn*64 + nt*16 + lr;
        int rbase = wm*16 + lg*4;
        #pragma unroll
        for (int r = 0; r < 4; r++) Hl[(rbase + r)*113 + col] = acc[nt][r];
    }
    __syncthreads();
    for (int task = t; task < 320; task += 256){
        int row = task/10, h = task - row*10;
        int grow = row0 + row;
        if (grow < N_NODES){
            const float* p = &Hl[row*113 + h*10];
            float s = 0.f, dd = 0.f;
            #pragma unroll
            for (int c = 0; c < 10; c++){
                float v = p[c];
                s  += v*a_src2[h*10 + c];
                dd += v*a_dst2[h*10 + c];
            }
            as2[grow*10 + h] = s;
            ad2[grow*10 + h] = dd;
        }
    }
}

// ---------- agg layer2 + fused WAVE-PARALLEL loss: one wave per dst (grid N/4) ----------
__global__ __launch_bounds__(256) void agg2_kernel(
    const int* __restrict__ offs, const int* __restrict__ csr_src,
    const float* __restrict__ as2, const float* __restrict__ ad2,
    const unsigned char* __restrict__ h2f8, const float* __restrict__ b2,
    const int* __restrict__ labels, const int* __restrict__ mask,
    float* __restrict__ emb2_out, float* __restrict__ lacc)
{
    __shared__ float sval[4][100];
    int wv = threadIdx.x >> 6;
    int lane = threadIdx.x & 63;
    int d = blockIdx.x*4 + wv;      // grid = N_NODES/4 exactly, d always < N
    int c0 = 2*lane;
    bool act = lane < 50;
    int h = lane/5; if (h > 9) h = 9;
    float adh = act ? ad2[d*10 + h] : 0.f;
    int e0 = offs[d], e1 = offs[d+1];
    float acc0 = 0.f, acc1 = 0.f, wsum = 0.f;

    for (int base = e0; base < e1; base += 64){
        int ii = base + lane;
        int sv = (ii < e1) ? csr_src[ii] : 0;
        int n = min(64, e1 - base);
        int i = 0;
        for (; i + 3 < n; i += 4){
            int s0 = __shfl(sv, i);
            int s1 = __shfl(sv, i+1);
            int s2 = __shfl(sv, i+2);
            int s3 = __shfl(sv, i+3);
            float l0=0.f,l1=0.f,l2=0.f,l3=0.f;
            int v0=0,v1=0,v2=0,v3=0;
            if (act){
                l0 = as2[s0*10 + h]; l1 = as2[s1*10 + h];
                l2 = as2[s2*10 + h]; l3 = as2[s3*10 + h];
                v0 = *(const unsigned short*)(h2f8 + (size_t)s0*100 + c0);
                v1 = *(const unsigned short*)(h2f8 + (size_t)s1*100 + c0);
                v2 = *(const unsigned short*)(h2f8 + (size_t)s2*100 + c0);
                v3 = *(const unsigned short*)(h2f8 + (size_t)s3*100 + c0);
            }
            float w0 = __expf(lrelu(l0 + adh));
            float w1 = __expf(lrelu(l1 + adh));
            float w2 = __expf(lrelu(l2 + adh));
            float w3 = __expf(lrelu(l3 + adh));
            acc0 += w0*__builtin_amdgcn_cvt_f32_fp8(v0, 0) + w1*__builtin_amdgcn_cvt_f32_fp8(v1, 0)
                  + w2*__builtin_amdgcn_cvt_f32_fp8(v2, 0) + w3*__builtin_amdgcn_cvt_f32_fp8(v3, 0);
            acc1 += w0*__builtin_amdgcn_cvt_f32_fp8(v0, 1) + w1*__builtin_amdgcn_cvt_f32_fp8(v1, 1)
                  + w2*__builtin_amdgcn_cvt_f32_fp8(v2, 1) + w3*__builtin_amdgcn_cvt_f32_fp8(v3, 1);
            wsum += (w0 + w1) + (w2 + w3);
        }
        for (; i < n; i++){
            int s0 = __shfl(sv, i);
            float l0 = 0.f; int v0 = 0;
            if (act){
                l0 = as2[s0*10 + h];
                v0 = *(const unsigned short*)(h2f8 + (size_t)s0*100 + c0);
            }
            float w0 = __expf(lrelu(l0 + adh));
            acc0 += w0*__builtin_amdgcn_cvt_f32_fp8(v0, 0);
            acc1 += w0*__builtin_amdgcn_cvt_f32_fp8(v0, 1);
            wsum += w0;
        }
    }
    if (act){
        float inv = 1.f/(wsum + 1e-16f);
        sval[wv][c0]   = acc0*inv;
        sval[wv][c0+1] = acc1*inv;
    }
    __syncthreads();
    // head-mean: lanes 0..9 hold the 10 logits in registers
    float val = -1e30f;
    if (lane < 10){
        float s = 0.f;
        #pragma unroll
        for (int hh = 0; hh < 10; hh++) s += sval[wv][hh*10 + lane];
        val = s*0.1f + b2[lane];
        emb2_out[(size_t)d*10 + lane] = val;
    }
    // wave-parallel CE within the 16-lane group containing lanes 0..9
    float m = val;
    m = fmaxf(m, __shfl_xor(m, 1));
    m = fmaxf(m, __shfl_xor(m, 2));
    m = fmaxf(m, __shfl_xor(m, 4));
    m = fmaxf(m, __shfl_xor(m, 8));
    float e = (lane < 10) ? __expf(val - m) : 0.f;
    e += __shfl_xor(e, 1);
    e += __shfl_xor(e, 2);
    e += __shfl_xor(e, 4);
    e += __shfl_xor(e, 8);
    int lbl = labels[d];
    float tv = __shfl(val, lbl);     // executed wave-uniformly
    if (lane == 0 && mask[d] != 0){
        float lse = m + __logf(e);
        int bin = ((blockIdx.x*4 + wv) & (NBINS-1))*2;
        atomicAdd(&lacc[bin], lse - tv);
        atomicAdd(&lacc[bin+1], 1.f);
    }
}

// ---------- finalize: reduce 256 bins ----------
__global__ void finalize_kernel(const float* __restrict__ lacc, float* __restrict__ out0){
    __shared__ float sn[4], sd[4];
    int t = threadIdx.x;
    float n = lacc[2*t], d = lacc[2*t+1];
    #pragma unroll
    for (int o = 32; o >= 1; o >>= 1){ n += __shfl_down(n, o); d += __shfl_down(d, o); }
    if ((t & 63) == 0){ sn[t>>6] = n; sd[t>>6] = d; }
    __syncthreads();
    if (t == 0){
        float N2 = sn[0]+sn[1]+sn[2]+sn[3];
        float D2 = sd[0]+sd[1]+sd[2]+sd[3];
        out0[0] = N2/D2;
    }
}

extern "C" void kernel_launch(void* const* d_in, const int* in_sizes, int n_in,
                              void* d_out, int out_size, void* d_ws, size_t ws_size,
                              hipStream_t stream) {
    const float* x      = (const float*)d_in[0];
    const int*   ei     = (const int*)d_in[1];
    const int*   labels = (const int*)d_in[2];
    const int*   mask   = (const int*)d_in[3];
    const float* W1     = (const float*)d_in[4];
    const float* a_src1 = (const float*)d_in[5];
    const float* a_dst1 = (const float*)d_in[6];
    const float* b1     = (const float*)d_in[7];
    const float* W2     = (const float*)d_in[8];
    const float* a_src2 = (const float*)d_in[9];
    const float* a_dst2 = (const float*)d_in[10];
    const float* b2     = (const float*)d_in[11];

    float* out  = (float*)d_out;
    float* emb1 = out + 1;                       // [N,128]
    float* emb2 = out + 1 + (size_t)N_NODES*128; // [N,10]

    unsigned short* h1bf = (unsigned short*)d_ws;              // N*128 bf16
    unsigned char*  h2f8 = (unsigned char*)(h1bf + (size_t)N_NODES*128);   // N*100 fp8
    float* as1  = (float*)(h2f8 + (size_t)N_NODES*100);        // byte offset divisible by 4
    float* ad1  = as1 + (size_t)N_NODES*8;
    float* as2  = ad1 + (size_t)N_NODES*8;
    float* ad2  = as2 + (size_t)N_NODES*10;
    float* lacc = ad2 + (size_t)N_NODES*10;  // 2*NBINS floats
    int* counts = (int*)(lacc + 2*NBINS);    // N
    int* offs   = counts + N_NODES;          // N+1
    int* rank   = offs + N_NODES + 1;        // E
    int* csr    = rank + N_EDGES;            // E
    int* exoffs = csr + N_EDGES;             // N
    int* bsums  = exoffs + N_NODES;          // NB_SCAN
    unsigned short* wt1 = (unsigned short*)(bsums + NB_SCAN);  // 128*128 bf16
    unsigned short* wt2 = wt1 + 128*128;                       // 112*128 bf16

    setup_kernel<<<(N_NODES+255)/256, 256, 0, stream>>>(W1, W2, wt1, wt2, counts, lacc);
    count_kernel<<<SB, 256, 0, stream>>>(ei, counts, rank);
    scan_blocks_kernel<<<NB_SCAN, 1024, 0, stream>>>(counts, exoffs, bsums);
    scan_add_kernel<<<NB_SCAN, 1024, 0, stream>>>(exoffs, bsums, offs);
    scatter_kernel<<<SB, 256, 0, stream>>>(ei, offs, rank, csr);

    gemm1_mfma<<<PG1, 256, 0, stream>>>(x, wt1, a_src1, a_dst1, h1bf, as1, ad1);
    agg1_kernel<<<(N_NODES + 3)/4, 256, 0, stream>>>(offs, csr, as1, ad1, h1bf, b1, emb1);
    gemm2_mfma<<<GB1, 256, 0, stream>>>(emb1, wt2, a_src2, a_dst2, h2f8, as2, ad2);
    agg2_kernel<<<N_NODES/4, 256, 0, stream>>>(offs, csr, as2, ad2, h2f8, b2, labels, mask, emb2, lacc);
    finalize_kernel<<<1, 256, 0, stream>>>(lacc, out);
}

// Round 21
// 234.749 us; speedup vs baseline: 1.1206x; 1.1206x over previous
//
#include <hip/hip_runtime.h>
#include <hip/hip_bf16.h>
#include <math.h>

#define N_NODES 100000
#define N_EDGES 800000
#define NB_SCAN ((N_NODES + 1023) / 1024)   // 98
#define GB1 ((N_NODES + 31)/32)             // 3125 row tiles
#define SB  ((N_EDGES + 255)/256)           // 3125 edge blocks
#define PG1 1024                            // persistent gemm1 grid (4 blocks/CU)
#define NBINS 256

typedef __bf16 bf16x8 __attribute__((ext_vector_type(8)));
typedef float  f32x4  __attribute__((ext_vector_type(4)));

__device__ __forceinline__ float lrelu(float v){ return v > 0.f ? v : 0.2f*v; }
__device__ __forceinline__ float eluf(float v){ return v > 0.f ? v : (__expf(v) - 1.f); }

__device__ __forceinline__ unsigned short f2bf(float f){
    union { float f; unsigned u; } v; v.f = f;
    unsigned r = (v.u + 0x7fff + ((v.u >> 16) & 1)) >> 16;
    return (unsigned short)r;
}
__device__ __forceinline__ float bf2f(unsigned short u){
    union { unsigned u; float f; } v; v.u = ((unsigned)u) << 16;
    return v.f;
}
// fp8 e4m3 (OCP on gfx950) encode via HW convert
__device__ __forceinline__ unsigned char f2fp8(float v){
    return (unsigned char)(__builtin_amdgcn_cvt_pk_fp8_f32(v, v, 0, false) & 0xff);
}

// ---------- setup ----------
__global__ __launch_bounds__(256) void setup_kernel(
    const float* __restrict__ W1, const float* __restrict__ W2,
    unsigned short* __restrict__ wt1, unsigned short* __restrict__ wt2,
    int* __restrict__ counts, float* __restrict__ lacc)
{
    int i = blockIdx.x*256 + threadIdx.x;
    if (i < N_NODES) counts[i] = 0;
    if (i < 2*NBINS) lacc[i] = 0.f;
    if (i < 128*128){
        int n = i >> 7, k = i & 127;
        wt1[i] = f2bf(W1[k*128 + n]);
    }
    if (i < 112*128){
        int n = i >> 7, k = i & 127;
        wt2[i] = (n < 100) ? f2bf(W2[k*100 + n]) : (unsigned short)0;
    }
}

// ---------- CSR build: count + rank capture ----------
__global__ __launch_bounds__(256) void count_kernel(const int* __restrict__ ei,
                                                    int* __restrict__ counts,
                                                    int* __restrict__ rank){
    int e = blockIdx.x*256 + threadIdx.x;
    if (e < N_EDGES){
        int d = ei[N_EDGES + e];
        rank[e] = atomicAdd(&counts[d], 1);
    }
}

__global__ __launch_bounds__(1024) void scan_blocks_kernel(const int* __restrict__ counts,
                                                           int* __restrict__ exoffs,
                                                           int* __restrict__ bsums){
    __shared__ int buf[1024];
    int t = threadIdx.x;
    int gid = blockIdx.x*1024 + t;
    int v = (gid < N_NODES) ? counts[gid] : 0;
    buf[t] = v;
    __syncthreads();
    #pragma unroll
    for (int off = 1; off < 1024; off <<= 1){
        int u = (t >= off) ? buf[t-off] : 0;
        __syncthreads();
        buf[t] += u;
        __syncthreads();
    }
    if (gid < N_NODES) exoffs[gid] = buf[t] - v;
    if (t == 1023) bsums[blockIdx.x] = buf[1023];
}

// scan_add computes its own block prefix over bsums (scan_sums folded in)
__global__ __launch_bounds__(1024) void scan_add_kernel(const int* __restrict__ exoffs,
                                                        const int* __restrict__ bsums,
                                                        int* __restrict__ offs){
    __shared__ int sb[128];
    int t = threadIdx.x;
    if (t < 128){
        int lim = min((int)blockIdx.x, NB_SCAN);
        sb[t] = (t < lim) ? bsums[t] : 0;
    }
    __syncthreads();
    #pragma unroll
    for (int off = 64; off >= 1; off >>= 1){
        if (t < off) sb[t] += sb[t + off];
        __syncthreads();
    }
    int pre = sb[0];
    int gid = blockIdx.x*1024 + t;
    if (gid < N_NODES){
        offs[gid] = exoffs[gid] + pre;
    }
    if (gid == 0) offs[N_NODES] = N_EDGES;
}

// ---------- scatter: atomic-free, ONE random write per edge ----------
__global__ __launch_bounds__(256) void scatter_kernel(
    const int* __restrict__ ei, const int* __restrict__ offs, const int* __restrict__ rank,
    int* __restrict__ csr_src)
{
    int e = blockIdx.x*256 + threadIdx.x;
    if (e >= N_EDGES) return;
    int s = ei[e];
    int d = ei[N_EDGES + e];
    csr_src[offs[d] + rank[e]] = s;
}

// ---------- GEMM1 persistent-W ----------
__global__ __launch_bounds__(256) void gemm1_mfma(
    const float* __restrict__ x, const unsigned short* __restrict__ wt1,
    const float* __restrict__ a_src, const float* __restrict__ a_dst,
    unsigned short* __restrict__ h1bf, float* __restrict__ as1, float* __restrict__ ad1)
{
    __shared__ unsigned short Al[32*128];   // 8 KB, XOR-swizzled
    __shared__ unsigned short Bl[128*128];  // 32 KB, XOR-swizzled (staged ONCE)
    int t = threadIdx.x;

    #pragma unroll
    for (int i = 0; i < 8; i++){
        int idx = (i*256 + t)*8;
        int n = idx >> 7, c = idx & 127;
        bf16x8 v = *(const bf16x8*)(wt1 + n*128 + c);
        int byte = (n*256 + c*2) ^ ((n&7)<<4);
        *(bf16x8*)((char*)Bl + byte) = v;
    }

    int wv = t >> 6, l = t & 63;
    int wm = wv >> 1, wn = wv & 1;
    int lr = l & 15, lg = l >> 4;

    for (int tile = blockIdx.x; tile < GB1; tile += PG1){
        int row0 = tile*32;
        #pragma unroll
        for (int i = 0; i < 2; i++){
            int idx = (i*256 + t)*8;
            int r = idx >> 7, c = idx & 127;
            int grow = row0 + r;
            bf16x8 v;
            if (grow < N_NODES){
                const float4* p = (const float4*)(x + (size_t)grow*128 + c);
                float4 f0 = p[0], f1 = p[1];
                v[0]=(__bf16)f0.x; v[1]=(__bf16)f0.y; v[2]=(__bf16)f0.z; v[3]=(__bf16)f0.w;
                v[4]=(__bf16)f1.x; v[5]=(__bf16)f1.y; v[6]=(__bf16)f1.z; v[7]=(__bf16)f1.w;
            } else {
                #pragma unroll
                for (int j = 0; j < 8; j++) v[j] = (__bf16)0.f;
            }
            int byte = (r*256 + c*2) ^ ((r&7)<<4);
            *(bf16x8*)((char*)Al + byte) = v;
        }
        __syncthreads();   // Al (and on iter0, Bl) visible

        bf16x8 af[4];
        #pragma unroll
        for (int ks = 0; ks < 4; ks++){
            int r = wm*16 + lr;
            int byte = (r*256 + (ks*32 + lg*8)*2) ^ ((r&7)<<4);
            af[ks] = *(const bf16x8*)((const char*)Al + byte);
        }
        f32x4 acc[4];
        #pragma unroll
        for (int nt = 0; nt < 4; nt++){
            acc[nt] = (f32x4){0.f,0.f,0.f,0.f};
            #pragma unroll
            for (int ks = 0; ks < 4; ks++){
                int n = wn*64 + nt*16 + lr;
                int byte = (n*256 + (ks*32 + lg*8)*2) ^ ((n&7)<<4);
                bf16x8 bfv = *(const bf16x8*)((const char*)Bl + byte);
                acc[nt] = __builtin_amdgcn_mfma_f32_16x16x32_bf16(af[ks], bfv, acc[nt], 0, 0, 0);
            }
        }
        int orow_base = row0 + wm*16 + lg*4;
        #pragma unroll
        for (int nt = 0; nt < 4; nt++){
            int colb = wn*64 + nt*16;
            int head = colb >> 4;
            float avs = a_src[colb + lr];
            float avd = a_dst[colb + lr];
            #pragma unroll
            for (int r = 0; r < 4; r++){
                int grow = orow_base + r;
                float v = acc[nt][r];
                if (grow < N_NODES) h1bf[(size_t)grow*128 + colb + lr] = f2bf(v);
                float ps = v*avs, pd = v*avd;
                ps += __shfl_xor(ps,1); ps += __shfl_xor(ps,2); ps += __shfl_xor(ps,4); ps += __shfl_xor(ps,8);
                pd += __shfl_xor(pd,1); pd += __shfl_xor(pd,2); pd += __shfl_xor(pd,4); pd += __shfl_xor(pd,8);
                if (lr == 0 && grow < N_NODES){
                    as1[grow*8 + head] = ps;
                    ad1[grow*8 + head] = pd;
                }
            }
        }
        __syncthreads();
    }
}

// ---------- agg layer1: one wave per dst; inline exp, 4-deep unroll ----------
__global__ __launch_bounds__(256) void agg1_kernel(
    const int* __restrict__ offs, const int* __restrict__ csr_src,
    const float* __restrict__ as1, const float* __restrict__ ad1,
    const unsigned short* __restrict__ h1bf, const float* __restrict__ b1,
    float* __restrict__ emb1_out /* d_out + 1 */)
{
    int wave = threadIdx.x >> 6;
    int lane = threadIdx.x & 63;
    int d = blockIdx.x*4 + wave;
    if (d >= N_NODES) return;
    int h = lane >> 3;
    int col = 2*lane;
    int e0 = offs[d], e1 = offs[d+1];
    float ad = ad1[d*8 + h];
    float acc0 = 0.f, acc1 = 0.f, wsum = 0.f;

    for (int base = e0; base < e1; base += 64){
        int ii = base + lane;
        int sv = (ii < e1) ? csr_src[ii] : 0;
        int n = min(64, e1 - base);
        int i = 0;
        for (; i + 3 < n; i += 4){
            int s0 = __shfl(sv, i);
            int s1 = __shfl(sv, i+1);
            int s2 = __shfl(sv, i+2);
            int s3 = __shfl(sv, i+3);
            float l0 = as1[s0*8 + h];
            float l1 = as1[s1*8 + h];
            float l2 = as1[s2*8 + h];
            float l3 = as1[s3*8 + h];
            unsigned hv0 = *(const unsigned*)(h1bf + (size_t)s0*128 + col);
            unsigned hv1 = *(const unsigned*)(h1bf + (size_t)s1*128 + col);
            unsigned hv2 = *(const unsigned*)(h1bf + (size_t)s2*128 + col);
            unsigned hv3 = *(const unsigned*)(h1bf + (size_t)s3*128 + col);
            float w0 = __expf(lrelu(l0 + ad));
            float w1 = __expf(lrelu(l1 + ad));
            float w2 = __expf(lrelu(l2 + ad));
            float w3 = __expf(lrelu(l3 + ad));
            acc0 += w0*bf2f((unsigned short)hv0) + w1*bf2f((unsigned short)hv1)
                  + w2*bf2f((unsigned short)hv2) + w3*bf2f((unsigned short)hv3);
            acc1 += w0*bf2f((unsigned short)(hv0>>16)) + w1*bf2f((unsigned short)(hv1>>16))
                  + w2*bf2f((unsigned short)(hv2>>16)) + w3*bf2f((unsigned short)(hv3>>16));
            wsum += (w0 + w1) + (w2 + w3);
        }
        for (; i < n; i++){
            int s0 = __shfl(sv, i);
            float w0 = __expf(lrelu(as1[s0*8 + h] + ad));
            unsigned hv0 = *(const unsigned*)(h1bf + (size_t)s0*128 + col);
            acc0 += w0*bf2f((unsigned short)hv0);
            acc1 += w0*bf2f((unsigned short)(hv0>>16));
            wsum += w0;
        }
    }
    float inv = 1.f/(wsum + 1e-16f);
    emb1_out[(size_t)d*128 + col]     = acc0*inv + b1[col];
    emb1_out[(size_t)d*128 + col + 1] = acc1*inv + b1[col+1];
}

// ---------- GEMM2 (non-persistent, LDS union): h2 (fp8) + fused alpha2 (f32) ----------
__global__ __launch_bounds__(256) void gemm2_mfma(
    const float* __restrict__ emb1g /* d_out+1 */, const unsigned short* __restrict__ wt2,
    const float* __restrict__ a_src2, const float* __restrict__ a_dst2,
    unsigned char* __restrict__ h2f8, float* __restrict__ as2, float* __restrict__ ad2)
{
    __shared__ __align__(16) char smem[36864];          // 8K (Al) + 28K (Bl)
    unsigned short* Al = (unsigned short*)smem;         // 32*128
    unsigned short* Bl = Al + 32*128;                   // 112*128
    float* Hl = (float*)smem;                           // reused: 32*113 f32

    int t = threadIdx.x;
    int row0 = blockIdx.x*32;

    #pragma unroll
    for (int i = 0; i < 2; i++){
        int idx = (i*256 + t)*8;
        int r = idx >> 7, c = idx & 127;
        int grow = row0 + r;
        bf16x8 v;
        if (grow < N_NODES){
            const float4* p = (const float4*)(emb1g + (size_t)grow*128 + c);
            float4 f0 = p[0], f1 = p[1];
            v[0]=(__bf16)eluf(f0.x); v[1]=(__bf16)eluf(f0.y); v[2]=(__bf16)eluf(f0.z); v[3]=(__bf16)eluf(f0.w);
            v[4]=(__bf16)eluf(f1.x); v[5]=(__bf16)eluf(f1.y); v[6]=(__bf16)eluf(f1.z); v[7]=(__bf16)eluf(f1.w);
        } else {
            #pragma unroll
            for (int j = 0; j < 8; j++) v[j] = (__bf16)0.f;
        }
        int byte = (r*256 + c*2) ^ ((r&7)<<4);
        *(bf16x8*)((char*)Al + byte) = v;
    }
    #pragma unroll
    for (int i = 0; i < 7; i++){
        int idx = (i*256 + t)*8;
        int n = idx >> 7, c = idx & 127;
        bf16x8 v = *(const bf16x8*)(wt2 + n*128 + c);
        int byte = (n*256 + c*2) ^ ((n&7)<<4);
        *(bf16x8*)((char*)Bl + byte) = v;
    }
    __syncthreads();

    int wv = t >> 6, l = t & 63;
    int wm = wv >> 1, wn = wv & 1;
    int lr = l & 15, lg = l >> 4;
    bf16x8 af[4];
    #pragma unroll
    for (int ks = 0; ks < 4; ks++){
        int r = wm*16 + lr;
        int byte = (r*256 + (ks*32 + lg*8)*2) ^ ((r&7)<<4);
        af[ks] = *(const bf16x8*)((const char*)Al + byte);
    }
    int ntmax = wn ? 3 : 4;
    f32x4 acc[4];
    for (int nt = 0; nt < ntmax; nt++){
        acc[nt] = (f32x4){0.f,0.f,0.f,0.f};
        #pragma unroll
        for (int ks = 0; ks < 4; ks++){
            int n = wn*64 + nt*16 + lr;
            int byte = (n*256 + (ks*32 + lg*8)*2) ^ ((n&7)<<4);
            bf16x8 bfv = *(const bf16x8*)((const char*)Bl + byte);
            acc[nt] = __builtin_amdgcn_mfma_f32_16x16x32_bf16(af[ks], bfv, acc[nt], 0, 0, 0);
        }
    }
    int orow_base = row0 + wm*16 + lg*4;
    for (int nt = 0; nt < ntmax; nt++){
        int col = wn*64 + nt*16 + lr;
        if (col < 100){
            #pragma unroll
            for (int r = 0; r < 4; r++){
                int grow = orow_base + r;
                if (grow < N_NODES) h2f8[(size_t)grow*100 + col] = f2fp8(acc[nt][r]);
            }
        }
    }
    __syncthreads();   // all LDS (Al/Bl) reads done -> safe to reuse as Hl
    for (int nt = 0; nt < ntmax; nt++){
        int col = wn*64 + nt*16 + lr;
        int rbase = wm*16 + lg*4;
        #pragma unroll
        for (int r = 0; r < 4; r++) Hl[(rbase + r)*113 + col] = acc[nt][r];
    }
    __syncthreads();
    for (int task = t; task < 320; task += 256){
        int row = task/10, h = task - row*10;
        int grow = row0 + row;
        if (grow < N_NODES){
            const float* p = &Hl[row*113 + h*10];
            float s = 0.f, dd = 0.f;
            #pragma unroll
            for (int c = 0; c < 10; c++){
                float v = p[c];
                s  += v*a_src2[h*10 + c];
                dd += v*a_dst2[h*10 + c];
            }
            as2[grow*10 + h] = s;
            ad2[grow*10 + h] = dd;
        }
    }
}

// ---------- agg layer2 + fused loss (serial lane-0 CE, block-aggregated atomics) ----------
__global__ __launch_bounds__(256) void agg2_kernel(
    const int* __restrict__ offs, const int* __restrict__ csr_src,
    const float* __restrict__ as2, const float* __restrict__ ad2,
    const unsigned char* __restrict__ h2f8, const float* __restrict__ b2,
    const int* __restrict__ labels, const int* __restrict__ mask,
    float* __restrict__ emb2_out, float* __restrict__ lacc)
{
    __shared__ float sval[4][100];
    __shared__ float bln[4], bld[4];
    int wv = threadIdx.x >> 6;
    int lane = threadIdx.x & 63;
    int d = blockIdx.x*4 + wv;      // grid = N_NODES/4 exactly (25000), d always < N
    int c0 = 2*lane;
    bool act = lane < 50;
    int h = lane/5; if (h > 9) h = 9;
    float adh = act ? ad2[d*10 + h] : 0.f;
    int e0 = offs[d], e1 = offs[d+1];
    float acc0 = 0.f, acc1 = 0.f, wsum = 0.f;

    for (int base = e0; base < e1; base += 64){
        int ii = base + lane;
        int sv = (ii < e1) ? csr_src[ii] : 0;
        int n = min(64, e1 - base);
        int i = 0;
        for (; i + 3 < n; i += 4){
            int s0 = __shfl(sv, i);
            int s1 = __shfl(sv, i+1);
            int s2 = __shfl(sv, i+2);
            int s3 = __shfl(sv, i+3);
            float l0=0.f,l1=0.f,l2=0.f,l3=0.f;
            int v0=0,v1=0,v2=0,v3=0;
            if (act){
                l0 = as2[s0*10 + h]; l1 = as2[s1*10 + h];
                l2 = as2[s2*10 + h]; l3 = as2[s3*10 + h];
                v0 = *(const unsigned short*)(h2f8 + (size_t)s0*100 + c0);
                v1 = *(const unsigned short*)(h2f8 + (size_t)s1*100 + c0);
                v2 = *(const unsigned short*)(h2f8 + (size_t)s2*100 + c0);
                v3 = *(const unsigned short*)(h2f8 + (size_t)s3*100 + c0);
            }
            float w0 = __expf(lrelu(l0 + adh));
            float w1 = __expf(lrelu(l1 + adh));
            float w2 = __expf(lrelu(l2 + adh));
            float w3 = __expf(lrelu(l3 + adh));
            acc0 += w0*__builtin_amdgcn_cvt_f32_fp8(v0, 0) + w1*__builtin_amdgcn_cvt_f32_fp8(v1, 0)
                  + w2*__builtin_amdgcn_cvt_f32_fp8(v2, 0) + w3*__builtin_amdgcn_cvt_f32_fp8(v3, 0);
            acc1 += w0*__builtin_amdgcn_cvt_f32_fp8(v0, 1) + w1*__builtin_amdgcn_cvt_f32_fp8(v1, 1)
                  + w2*__builtin_amdgcn_cvt_f32_fp8(v2, 1) + w3*__builtin_amdgcn_cvt_f32_fp8(v3, 1);
            wsum += (w0 + w1) + (w2 + w3);
        }
        for (; i < n; i++){
            int s0 = __shfl(sv, i);
            float l0 = 0.f; int v0 = 0;
            if (act){
                l0 = as2[s0*10 + h];
                v0 = *(const unsigned short*)(h2f8 + (size_t)s0*100 + c0);
            }
            float w0 = __expf(lrelu(l0 + adh));
            acc0 += w0*__builtin_amdgcn_cvt_f32_fp8(v0, 0);
            acc1 += w0*__builtin_amdgcn_cvt_f32_fp8(v0, 1);
            wsum += w0;
        }
    }
    if (act){
        float inv = 1.f/(wsum + 1e-16f);
        sval[wv][c0]   = acc0*inv;
        sval[wv][c0+1] = acc1*inv;
    }
    __syncthreads();
    if (lane < 10){
        float s = 0.f;
        #pragma unroll
        for (int hh = 0; hh < 10; hh++) s += sval[wv][hh*10 + lane];
        float val = s*0.1f + b2[lane];
        emb2_out[(size_t)d*10 + lane] = val;
        sval[wv][lane] = val;           // only index `lane` read by lane itself above
    }
    __syncthreads();
    // fused loss: per-wave lane 0 computes CE for node d
    if (lane == 0){
        float num = 0.f, den = 0.f;
        if (mask[d] != 0){
            float m = sval[wv][0];
            #pragma unroll
            for (int c = 1; c < 10; c++) m = fmaxf(m, sval[wv][c]);
            float ssum = 0.f;
            #pragma unroll
            for (int c = 0; c < 10; c++) ssum += __expf(sval[wv][c] - m);
            num = (m + __logf(ssum)) - sval[wv][labels[d]];
            den = 1.f;
        }
        bln[wv] = num; bld[wv] = den;
    }
    __syncthreads();
    if (threadIdx.x == 0){
        float n = bln[0]+bln[1]+bln[2]+bln[3];
        float dd = bld[0]+bld[1]+bld[2]+bld[3];
        if (dd != 0.f){
            int bin = (blockIdx.x & (NBINS-1))*2;
            atomicAdd(&lacc[bin], n);
            atomicAdd(&lacc[bin+1], dd);
        }
    }
}

// ---------- finalize: reduce 256 bins ----------
__global__ void finalize_kernel(const float* __restrict__ lacc, float* __restrict__ out0){
    __shared__ float sn[4], sd[4];
    int t = threadIdx.x;
    float n = lacc[2*t], d = lacc[2*t+1];
    #pragma unroll
    for (int o = 32; o >= 1; o >>= 1){ n += __shfl_down(n, o); d += __shfl_down(d, o); }
    if ((t & 63) == 0){ sn[t>>6] = n; sd[t>>6] = d; }
    __syncthreads();
    if (t == 0){
        float N2 = sn[0]+sn[1]+sn[2]+sn[3];
        float D2 = sd[0]+sd[1]+sd[2]+sd[3];
        out0[0] = N2/D2;
    }
}

extern "C" void kernel_launch(void* const* d_in, const int* in_sizes, int n_in,
                              void* d_out, int out_size, void* d_ws, size_t ws_size,
                              hipStream_t stream) {
    const float* x      = (const float*)d_in[0];
    const int*   ei     = (const int*)d_in[1];
    const int*   labels = (const int*)d_in[2];
    const int*   mask   = (const int*)d_in[3];
    const float* W1     = (const float*)d_in[4];
    const float* a_src1 = (const float*)d_in[5];
    const float* a_dst1 = (const float*)d_in[6];
    const float* b1     = (const float*)d_in[7];
    const float* W2     = (const float*)d_in[8];
    const float* a_src2 = (const float*)d_in[9];
    const float* a_dst2 = (const float*)d_in[10];
    const float* b2     = (const float*)d_in[11];

    float* out  = (float*)d_out;
    float* emb1 = out + 1;                       // [N,128]
    float* emb2 = out + 1 + (size_t)N_NODES*128; // [N,10]

    unsigned short* h1bf = (unsigned short*)d_ws;              // N*128 bf16
    unsigned char*  h2f8 = (unsigned char*)(h1bf + (size_t)N_NODES*128);   // N*100 fp8
    float* as1  = (float*)(h2f8 + (size_t)N_NODES*100);        // byte offset divisible by 4
    float* ad1  = as1 + (size_t)N_NODES*8;
    float* as2  = ad1 + (size_t)N_NODES*8;
    float* ad2  = as2 + (size_t)N_NODES*10;
    float* lacc = ad2 + (size_t)N_NODES*10;  // 2*NBINS floats
    int* counts = (int*)(lacc + 2*NBINS);    // N
    int* offs   = counts + N_NODES;          // N+1
    int* rank   = offs + N_NODES + 1;        // E
    int* csr    = rank + N_EDGES;            // E
    int* exoffs = csr + N_EDGES;             // N
    int* bsums  = exoffs + N_NODES;          // NB_SCAN
    unsigned short* wt1 = (unsigned short*)(bsums + NB_SCAN);  // 128*128 bf16
    unsigned short* wt2 = wt1 + 128*128;                       // 112*128 bf16

    setup_kernel<<<(N_NODES+255)/256, 256, 0, stream>>>(W1, W2, wt1, wt2, counts, lacc);
    count_kernel<<<SB, 256, 0, stream>>>(ei, counts, rank);
    scan_blocks_kernel<<<NB_SCAN, 1024, 0, stream>>>(counts, exoffs, bsums);
    scan_add_kernel<<<NB_SCAN, 1024, 0, stream>>>(exoffs, bsums, offs);
    scatter_kernel<<<SB, 256, 0, stream>>>(ei, offs, rank, csr);

    gemm1_mfma<<<PG1, 256, 0, stream>>>(x, wt1, a_src1, a_dst1, h1bf, as1, ad1);
    agg1_kernel<<<(N_NODES + 3)/4, 256, 0, stream>>>(offs, csr, as1, ad1, h1bf, b1, emb1);
    gemm2_mfma<<<GB1, 256, 0, stream>>>(emb1, wt2, a_src2, a_dst2, h2f8, as2, ad2);
    agg2_kernel<<<N_NODES/4, 256, 0, stream>>>(offs, csr, as2, ad2, h2f8, b2, labels, mask, emb2, lacc);
    finalize_kernel<<<1, 256, 0, stream>>>(lacc, out);
}